// Round 5
// baseline (438.162 us; speedup 1.0000x reference)
//
#include <hip/hip_runtime.h>
#include <stdint.h>

#define T_LEN 1024
#define NSTATE 32

__device__ __forceinline__ float max3f(float a, float b, float c) {
    return fmaxf(fmaxf(a, b), c);   // v_max3_f32
}

// Each block handles TWO batches: lanes 0-31 -> batch 2*bid, lanes 32-63 -> 2*bid+1.
// Lane j of each half owns output column j and reduces all 32 candidates itself.
__launch_bounds__(64)
__global__ void viterbi_kernel(const float* __restrict__ logits,
                               const float* __restrict__ trans,
                               const int* __restrict__ seqlen,
                               int* __restrict__ out)
{
    const int lane = threadIdx.x;   // 0..63
    const int half = lane >> 5;     // which batch
    const int j    = lane & 31;     // output column

    __shared__ __align__(16) float st[2][NSTATE];        // state rows (broadcast)
    __shared__ uint8_t bp[2][T_LEN * NSTATE];            // backptrs, t=1..L-1
    __shared__ uint8_t Farr[2][NSTATE * NSTATE];         // chunk functions
    __shared__ uint8_t earr[2][NSTATE];                  // chunk entry tags
    __shared__ __align__(16) int pred[2][T_LEN];         // output rows

    const int bid = blockIdx.x;
    int LA = seqlen[2 * bid], LB = seqlen[2 * bid + 1];
    LA = min(max(LA, 0), T_LEN);
    LB = min(max(LB, 0), T_LEN);
    const int Lm   = half ? LB : LA;     // my batch's length
    const int maxL = max(LA, LB);

    // full transition column j in registers (same for both halves)
    float tr[NSTATE];
#pragma unroll
    for (int k = 0; k < NSTATE; ++k)
        tr[k] = trans[k * NSTATE + j];

    const float* lg = logits + (size_t)(2 * bid + half) * T_LEN * NSTATE;

    // state[j] of my batch lives in this lane
    float ns = lg[j];

    const float4* stv = reinterpret_cast<const float4*>(st[half]);
    uint8_t* bph = bp[half];

    // one superstep: advances BOTH batches by one t
    auto step = [&](int t, float lgt) {
        st[half][j] = ns;                 // 64 distinct addrs, 2-way bank alias (free)
        float4 q0 = stv[0];               // 8 broadcast ds_read_b128 (2 addrs/instr)
        float4 q1 = stv[1];
        float4 q2 = stv[2];
        float4 q3 = stv[3];
        float4 q4 = stv[4];
        float4 q5 = stv[5];
        float4 q6 = stv[6];
        float4 q7 = stv[7];

        float v[NSTATE];
        v[0]=q0.x+tr[0];  v[1]=q0.y+tr[1];  v[2]=q0.z+tr[2];  v[3]=q0.w+tr[3];
        v[4]=q1.x+tr[4];  v[5]=q1.y+tr[5];  v[6]=q1.z+tr[6];  v[7]=q1.w+tr[7];
        v[8]=q2.x+tr[8];  v[9]=q2.y+tr[9];  v[10]=q2.z+tr[10];v[11]=q2.w+tr[11];
        v[12]=q3.x+tr[12];v[13]=q3.y+tr[13];v[14]=q3.z+tr[14];v[15]=q3.w+tr[15];
        v[16]=q4.x+tr[16];v[17]=q4.y+tr[17];v[18]=q4.z+tr[18];v[19]=q4.w+tr[19];
        v[20]=q5.x+tr[20];v[21]=q5.y+tr[21];v[22]=q5.z+tr[22];v[23]=q5.w+tr[23];
        v[24]=q6.x+tr[24];v[25]=q6.y+tr[25];v[26]=q6.z+tr[26];v[27]=q6.w+tr[27];
        v[28]=q7.x+tr[28];v[29]=q7.y+tr[29];v[30]=q7.z+tr[30];v[31]=q7.w+tr[31];

        // max over 32 candidates (order-independent, exact)
        float g0 = max3f(v[0],  v[1],  v[2]);
        float g1 = max3f(v[3],  v[4],  v[5]);
        float g2 = max3f(v[6],  v[7],  v[8]);
        float g3 = max3f(v[9],  v[10], v[11]);
        float g4 = max3f(v[12], v[13], v[14]);
        float g5 = max3f(v[15], v[16], v[17]);
        float g6 = max3f(v[18], v[19], v[20]);
        float g7 = max3f(v[21], v[22], v[23]);
        float g8 = max3f(v[24], v[25], v[26]);
        float g9 = max3f(v[27], v[28], v[29]);
        float g10 = fmaxf(v[30], v[31]);
        float h0 = max3f(g0, g1, g2);
        float h1 = max3f(g3, g4, g5);
        float h2 = max3f(g6, g7, g8);
        float h3 = fmaxf(g9, g10);
        float gm = fmaxf(max3f(h0, h1, h2), h3);

        const bool act = t < Lm;
        ns = act ? gm + lgt : ns;         // frozen once past my batch's length

        // exact first-occurrence argmax (two independent 16-deep cascades)
        int ia = 64, ib = 64;
#pragma unroll
        for (int k = 15; k >= 0; --k) ia = (v[k] == gm) ? k : ia;
#pragma unroll
        for (int k = 31; k >= 16; --k) ib = (v[k] == gm) ? k : ib;
        int idx = min(ia, ib);

        if (act) bph[t * NSTATE + j] = (uint8_t)idx;
    };

    // ---------------- forward (single wave: no barriers) ----------------
    if (maxL >= 2) {
        float pre[8];
#pragma unroll
        for (int d = 0; d < 8; ++d) {
            int tp = 1 + d; if (tp > 1023) tp = 1023;
            pre[d] = lg[tp * NSTATE + j];
        }
        int t = 1;
        for (; t + 8 <= maxL; t += 8) {
#pragma unroll
            for (int u = 0; u < 8; ++u) {
                step(t + u, pre[u]);
                int tp = t + 8 + u; if (tp > 1023) tp = 1023;
                pre[u] = lg[tp * NSTATE + j];
            }
        }
        for (int k = 0; t < maxL; ++t, ++k) step(t, pre[k]);
    }

    // ---------------- last_tag per half (butterfly within 32 lanes) ----------------
    float m = ns;
#pragma unroll
    for (int d = 1; d < 32; d <<= 1) m = fmaxf(m, __shfl_xor(m, d));
    int ii = (ns == m) ? j : 64;
#pragma unroll
    for (int d = 1; d < 32; d <<= 1) ii = min(ii, __shfl_xor(ii, d));
    const int ft = ii;   // last tag, uniform within each half

    __syncthreads();

    // ---- phase 1: chunk functions, all 32 start states (32 lanes per batch) ----
    {
        int tags[NSTATE];
#pragma unroll
        for (int k = 0; k < NSTATE; ++k) tags[k] = k;
        const int thi = j * 32 + 31;
        for (int s = 0; s < 32; ++s) {
            int t = thi - s;
            bool valid = (t >= 1) && (t <= Lm - 1);
            int tc = min(max(t, 1), max(Lm - 1, 1));
            int base = tc * NSTATE;
#pragma unroll
            for (int k = 0; k < NSTATE; ++k) {
                int nt = bph[base + tags[k]];
                tags[k] = valid ? nt : tags[k];
            }
        }
#pragma unroll
        for (int k = 0; k < NSTATE; ++k)
            Farr[half][j * NSTATE + k] = (uint8_t)tags[k];
    }
    __syncthreads();

    // ---- phase 2: compose chunk entries (lane 0 of each half) ----
    if (j == 0) {
        int e = ft;
        for (int c2 = 31; c2 >= 0; --c2) {
            earr[half][c2] = (uint8_t)e;
            e = Farr[half][c2 * NSTATE + e];
        }
    }
    __syncthreads();

    // ---- phase 3: re-walk chunks in parallel, emit pred (masking folds in L<2) ----
    {
        int tag = earr[half][j];
        const int thi3 = j * 32 + 31;
        for (int s = 0; s < 32; ++s) {
            int t = thi3 - s;
            pred[half][t] = (t < Lm) ? tag : 0;
            bool valid = (t >= 1) && (t <= Lm - 1);
            int tc = min(max(t, 1), max(Lm - 1, 1));
            int nt = bph[tc * NSTATE + tag];
            tag = valid ? nt : tag;
        }
    }
    __syncthreads();

    // ---------------- coalesced store (each half stores its batch row) ----------------
    int4* o4 = reinterpret_cast<int4*>(out + (size_t)(2 * bid + half) * T_LEN);
    const int4* p4 = reinterpret_cast<const int4*>(pred[half]);
#pragma unroll
    for (int r = 0; r < 8; ++r)
        o4[r * 32 + j] = p4[r * 32 + j];
}

extern "C" void kernel_launch(void* const* d_in, const int* in_sizes, int n_in,
                              void* d_out, int out_size, void* d_ws, size_t ws_size,
                              hipStream_t stream) {
    const float* logits = (const float*)d_in[0];
    const float* trans  = (const float*)d_in[1];
    const int*   slen   = (const int*)d_in[2];
    int*         out    = (int*)d_out;
    const int B = in_sizes[2];   // 1024

    viterbi_kernel<<<dim3(B / 2), dim3(64), 0, stream>>>(logits, trans, slen, out);
}

// Round 6
// 250.636 us; speedup vs baseline: 1.7482x; 1.7482x over previous
//
#include <hip/hip_runtime.h>
#include <stdint.h>

#define T_LEN 1024
#define NSTATE 32

typedef int v2i __attribute__((ext_vector_type(2)));

__device__ __forceinline__ float max3f(float a, float b, float c) {
    return fmaxf(fmaxf(a, b), c);   // v_max3_f32
}
__device__ __forceinline__ int min3i(int a, int b, int c) {
    return min(min(a, b), c);       // v_min3_i32
}

// DPP row-rotate by n within each 16-lane row (pure VALU, no LDS pipe)
#define ROR(x, n) __builtin_amdgcn_mov_dpp((x), 0x120 + (n), 0xF, 0xF, false)

// All-gather the 16 values of this lane's 16-row into g[0..15].
// g[k] = value rotated by k (direction is hardware-defined but CONSISTENT;
// the pidx probe below flows through this same network, so any direction works).
__device__ __forceinline__ void gather16(int x, int g[16]) {
    g[0]  = x;
    g[1]  = ROR(g[0], 1);
    g[2]  = ROR(g[0], 2);
    g[3]  = ROR(g[1], 2);
    g[4]  = ROR(g[0], 4);
    g[5]  = ROR(g[1], 4);
    g[6]  = ROR(g[2], 4);
    g[7]  = ROR(g[3], 4);
    g[8]  = ROR(g[0], 8);
    g[9]  = ROR(g[1], 8);
    g[10] = ROR(g[2], 8);
    g[11] = ROR(g[3], 8);
    g[12] = ROR(g[4], 8);
    g[13] = ROR(g[5], 8);
    g[14] = ROR(g[6], 8);
    g[15] = ROR(g[7], 8);
}

// Exchange with lane^16 (row swap). Returns partner's value. Robust to either
// operand-pairing convention: both inputs hold `own`, so any cross-row datum
// equals the partner's value; bitwise compare picks whichever reg crossed.
__device__ __forceinline__ int xrow16_partner(int own) {
    int a = own, b = own;
#if __has_builtin(__builtin_amdgcn_permlane16_swap)
    v2i r = __builtin_amdgcn_permlane16_swap(a, b, false, false);
    a = r[0]; b = r[1];
#else
    asm volatile("v_permlane16_swap_b32 %0, %1" : "+v"(a), "+v"(b));
#endif
    return (a == own) ? b : a;
}

__launch_bounds__(64)
__global__ void viterbi_kernel(const float* __restrict__ logits,
                               const float* __restrict__ trans,
                               const int* __restrict__ seqlen,
                               int* __restrict__ out)
{
    const int lane = threadIdx.x;   // 0..63
    const int j    = lane & 31;     // output column owned by this lane
    // state layout: lane l holds s[myidx]; rows hold contiguous halves so the
    // two 32-halves cover complementary candidate halves for the same j.
    const int myidx = (lane < 32) ? j : (j ^ 16);
    const bool upper = lane >= 32;

    __shared__ uint8_t bp[T_LEN * NSTATE];      // backptrs, t=1..L-1
    __shared__ uint8_t Farr[NSTATE * NSTATE];   // chunk functions
    __shared__ uint8_t earr[NSTATE];            // chunk entry tags
    __shared__ __align__(16) int pred[T_LEN];   // output row

    int L = seqlen[blockIdx.x];
    L = min(max(L, 0), T_LEN);

    // probe: push myidx through the gather network -> pidx[k] = source state
    // index held in register k after the same rotations. Direction-proof.
    int pidx[16];
    gather16(myidx, pidx);

    // pre-rotated transition column j matching the gathered layout
    float tr_rot[16];
#pragma unroll
    for (int k = 0; k < 16; ++k)
        tr_rot[k] = trans[pidx[k] * NSTATE + j];

    const float* lg = logits + (size_t)blockIdx.x * T_LEN * NSTATE;

    // init: lane holds state[myidx] = logits[b,0,myidx]
    float ns = lg[myidx];

    // one forward step (pure-VALU chain; only DS op is the bp byte write)
    auto step = [&](int t, float lgt) {
        int gb[16];
        gather16(__float_as_int(ns), gb);    // 15 v_mov_dpp

        float v[16];
#pragma unroll
        for (int k = 0; k < 16; ++k)
            v[k] = __int_as_float(gb[k]) + tr_rot[k];

        // max over this half's 16 candidates (max3 tree, exact)
        float a0 = max3f(v[0],  v[1],  v[2]);
        float a1 = max3f(v[3],  v[4],  v[5]);
        float a2 = max3f(v[6],  v[7],  v[8]);
        float a3 = max3f(v[9],  v[10], v[11]);
        float a4 = max3f(v[12], v[13], v[14]);
        float b0 = max3f(a0, a1, a2);
        float b1 = max3f(a3, a4, v[15]);
        float hm = fmaxf(b0, b1);

        // cross-half combine (lane^32 holds the other 16 candidates), VALU pipe
        v2i sw = __builtin_amdgcn_permlane32_swap(__float_as_int(hm),
                                                  __float_as_int(hm), false, false);
        float gm = fmaxf(hm, fmaxf(__int_as_float(sw[0]), __int_as_float(sw[1])));

        ns = gm + lgt;    // same single-rounding add order as reference

        // argmax with exact first-occurrence tie-break (min true source index)
        int ix[16];
#pragma unroll
        for (int k = 0; k < 16; ++k)
            ix[k] = (v[k] == gm) ? pidx[k] : 64;
        int c0 = min3i(ix[0],  ix[1],  ix[2]);
        int c1 = min3i(ix[3],  ix[4],  ix[5]);
        int c2 = min3i(ix[6],  ix[7],  ix[8]);
        int c3 = min3i(ix[9],  ix[10], ix[11]);
        int c4 = min3i(ix[12], ix[13], ix[14]);
        int d0 = min3i(c0, c1, c2);
        int d1 = min3i(c3, c4, ix[15]);
        int ih = min(d0, d1);
        v2i swi = __builtin_amdgcn_permlane32_swap(ih, ih, false, false);
        int idx = min(ih, min(swi[0], swi[1]));

        bp[t * NSTATE + j] = (uint8_t)idx;   // dup same-value byte write, benign

        // relayout for next step: upper lanes need ns' of column j^16,
        // which lives at lane^16 (both rows just computed their own j).
        int part = xrow16_partner(__float_as_int(ns));
        if (upper) ns = __int_as_float(part);
    };

    // ---------------- forward (single wave: no barriers) ----------------
    if (L >= 2) {
        float pre[8];
#pragma unroll
        for (int d = 0; d < 8; ++d) {
            int tp = 1 + d; if (tp > 1023) tp = 1023;
            pre[d] = lg[tp * NSTATE + j];
        }
        int t = 1;
        for (; t + 8 <= L; t += 8) {
#pragma unroll
            for (int u = 0; u < 8; ++u) {
                step(t + u, pre[u]);
                int tp = t + 8 + u; if (tp > 1023) tp = 1023;
                pre[u] = lg[tp * NSTATE + j];
            }
        }
        for (int k = 0; t < L; ++t, ++k) step(t, pre[k]);
    }

    // ---------------- last_tag = argmax(final state) ----------------
    // every state value appears exactly twice across the 64 lanes (at myidx)
    float m = ns;
#pragma unroll
    for (int d = 1; d < 64; d <<= 1) m = fmaxf(m, __shfl_xor(m, d));
    int ii = (ns == m) ? myidx : 64;
#pragma unroll
    for (int d = 1; d < 64; d <<= 1) ii = min(ii, __shfl_xor(ii, d));
    const int ft = ii;   // last tag (identical in all lanes)

    __syncthreads();   // bp visible for backtrace

    // ---- phase 1: chunk functions, all 32 start states (halves split k) ----
    {
        const int c = lane & 31;
        const int j0base = (lane >> 5) * 16;
        int tags[16];
#pragma unroll
        for (int k = 0; k < 16; ++k) tags[k] = j0base + k;
        const int thi = c * 32 + 31;
        for (int s = 0; s < 32; ++s) {
            int t = thi - s;
            bool valid = (t >= 1) && (t <= L - 1);
            int tc = min(max(t, 1), max(L - 1, 1));
            int base = tc * NSTATE;
#pragma unroll
            for (int k = 0; k < 16; ++k) {
                int nt = bp[base + tags[k]];
                tags[k] = valid ? nt : tags[k];
            }
        }
#pragma unroll
        for (int k = 0; k < 16; ++k)
            Farr[c * 32 + j0base + k] = (uint8_t)tags[k];
    }
    __syncthreads();

    // ---- phase 2: compose chunk entries (serial, 32 steps) ----
    if (lane == 0) {
        int e = ft;
        for (int c2 = 31; c2 >= 0; --c2) {
            earr[c2] = (uint8_t)e;
            e = Farr[c2 * 32 + e];
        }
    }
    __syncthreads();

    // ---- phase 3: re-walk chunks in parallel, emit pred (predication
    //      handles L<2: pred[t]=0 for t>=L, pred[0]=ft when L==1) ----
    if (lane < 32) {
        int tag = earr[lane];
        const int thi3 = lane * 32 + 31;
        for (int s = 0; s < 32; ++s) {
            int t = thi3 - s;
            pred[t] = (t < L) ? tag : 0;
            bool valid = (t >= 1) && (t <= L - 1);
            int tc = min(max(t, 1), max(L - 1, 1));
            int nt = bp[tc * NSTATE + tag];
            tag = valid ? nt : tag;
        }
    }
    __syncthreads();

    // ---------------- coalesced store ----------------
    int4* out4 = reinterpret_cast<int4*>(out + (size_t)blockIdx.x * T_LEN);
    const int4* p4 = reinterpret_cast<const int4*>(pred);
#pragma unroll
    for (int r = 0; r < 4; ++r)
        out4[r * 64 + lane] = p4[r * 64 + lane];
}

extern "C" void kernel_launch(void* const* d_in, const int* in_sizes, int n_in,
                              void* d_out, int out_size, void* d_ws, size_t ws_size,
                              hipStream_t stream) {
    const float* logits = (const float*)d_in[0];
    const float* trans  = (const float*)d_in[1];
    const int*   slen   = (const int*)d_in[2];
    int*         out    = (int*)d_out;
    const int B = in_sizes[2];   // 1024

    viterbi_kernel<<<dim3(B), dim3(64), 0, stream>>>(logits, trans, slen, out);
}